// Round 1
// baseline (781.540 us; speedup 1.0000x reference)
//
#include <hip/hip_runtime.h>
#include <climits>

#define SEG_B 64
#define SEG_L 50000
#define SEG_D 32
#define TOPK  1024
#define EQ_CAP 2048
#define CHUNKS 32
#define CHUNK_PTS ((SEG_L + CHUNKS - 1) / CHUNKS)   // 1563

// Map float to uint32 such that larger float -> larger key (total order, no NaN in inputs).
__device__ __forceinline__ unsigned ordkey(float f) {
    unsigned u = __float_as_uint(f);
    return (u & 0x80000000u) ? ~u : (u | 0x80000000u);
}

// Pass 1 (fused): att[p] = dot(x[p,:32], w) + bias, AND per-segment round-1 (top 11 bits)
// histogram. One block per (chunk, segment): 64 segs x 32 chunks = 2048 blocks, each
// streaming a contiguous ~200KB slice of x. 8 lanes per point, float4 loads
// (1 KiB/wave/instr). LDS-histogram contention is spread over 32x more CUs than the old
// k_select round 1 and hides under the HBM stream; nonzero bins merge to global atomics.
__global__ void k_att_hist(const float* __restrict__ x, const float* __restrict__ w,
                           const float* __restrict__ bias, float* __restrict__ att,
                           unsigned* __restrict__ g_hist) {
    const int b     = blockIdx.y;       // segment
    const int chunk = blockIdx.x;       // chunk within segment
    const int tid   = (int)threadIdx.x;
    const int lane  = tid & 63;
    const int q     = lane & 7;         // which float4 of the 32-dim row
    const int sub   = lane >> 3;        // which of the 8 points this wave handles per iter
    const int wv    = tid >> 6;         // wave in block (0..3)

    __shared__ unsigned hist[2048];
    for (int i = tid; i < 2048; i += 256) hist[i] = 0u;
    __syncthreads();

    const float4 wq = ((const float4*)w)[q];
    const float bb  = bias[0];
    const float4* x4 = (const float4*)x;
    const int i0 = chunk * CHUNK_PTS;
    const int i1 = min(i0 + CHUNK_PTS, SEG_L);
    const long long segBase = (long long)b * SEG_L;

    for (int i = i0 + wv * 8 + sub; i < i1; i += 32) {
        const long long p = segBase + i;
        float4 v = x4[p * 8 + q];
        float dot = v.x * wq.x + v.y * wq.y + v.z * wq.z + v.w * wq.w;
        dot += __shfl_xor(dot, 1);
        dot += __shfl_xor(dot, 2);
        dot += __shfl_xor(dot, 4);
        if (q == 0) {
            const float av = dot + bb;
            att[p] = av;
            atomicAdd(&hist[ordkey(av) >> 21], 1u);   // round-1 digit (11 bits)
        }
    }
    __syncthreads();

    unsigned* gh = g_hist + (size_t)b * 2048;
    for (int i = tid; i < 2048; i += 256) {
        unsigned c = hist[i];
        if (c) atomicAdd(&gh[i], c);
    }
}

// Pass 2: per-segment radix select (descending) of the TOPK-th largest att value.
// Round 1 histogram comes precomputed from k_att_hist; only rounds 2 (11 bits) and
// 3 (10 bits) sweep att, and both are prefix-filtered (light LDS-atomic contention).
__global__ void k_select(const float* __restrict__ att, const unsigned* __restrict__ g_hist,
                         unsigned* __restrict__ tkey, unsigned* __restrict__ need_eq) {
    const int b   = blockIdx.x;
    const int tid = (int)threadIdx.x;
    const int bs  = (int)blockDim.x;
    __shared__ unsigned hist[2048];
    __shared__ unsigned s_prefix, s_k;

    // Round 1: scan the precomputed histogram.
    const unsigned* gh = g_hist + (size_t)b * 2048;
    for (int i = tid; i < 2048; i += bs) hist[i] = gh[i];
    __syncthreads();
    if (tid == 0) {
        unsigned k = TOPK, acc = 0u, digit = 0u;
        for (int bin = 2047; bin >= 0; --bin) {
            unsigned c = hist[bin];
            if (acc + c >= k) { digit = (unsigned)bin; s_k = k - acc; break; }
            acc += c;
        }
        s_prefix = digit << 21;
    }
    __syncthreads();

    const float* a = att + (long long)b * SEG_L;
    const unsigned shifts[2]   = {10u, 0u};
    const unsigned widths[2]   = {11u, 10u};
    const unsigned maskdone[2] = {0xFFE00000u, 0xFFFFFC00u};

    for (int r = 0; r < 2; ++r) {
        const unsigned shift = shifts[r];
        const unsigned nbins = 1u << widths[r];
        const unsigned dmask = nbins - 1u;
        const unsigned mdone = maskdone[r];
        for (int i = tid; i < 2048; i += bs) hist[i] = 0u;
        __syncthreads();                      // hist zeroed + previous round's s_prefix visible
        const unsigned prefix = s_prefix;
        for (int i = tid; i < SEG_L; i += bs) {
            unsigned key = ordkey(a[i]);
            if ((key & mdone) == prefix) {
                atomicAdd(&hist[(key >> shift) & dmask], 1u);
            }
        }
        __syncthreads();
        if (tid == 0) {
            unsigned k = s_k, acc = 0u; unsigned digit = 0u;
            for (int bin = (int)nbins - 1; bin >= 0; --bin) {
                unsigned c = hist[bin];
                if (acc + c >= k) { digit = (unsigned)bin; s_k = k - acc; break; }
                acc += c;
            }
            s_prefix = prefix | (digit << shift);
        }
        __syncthreads();                      // protect hist (thread0 scan) from next round's zeroing
    }
    if (tid == 0) { tkey[b] = s_prefix; need_eq[b] = s_k; }
}

// Pass 3: masked accumulation. Strictly-greater rows accumulate into LDS -> global atomics.
// Equal-to-threshold rows record their index for tie-breaking.
__global__ void k_accum(const float* __restrict__ x, const float* __restrict__ att,
                        const unsigned* __restrict__ tkey,
                        float* __restrict__ g_acc, unsigned* __restrict__ eq_cnt,
                        int* __restrict__ eq_idx) {
    const int b = blockIdx.x;
    const int chunk = blockIdx.y;
    __shared__ float acc[SEG_D];
    if (threadIdx.x < SEG_D) acc[threadIdx.x] = 0.0f;
    __syncthreads();
    const unsigned tk = tkey[b];
    const int per = (SEG_L + gridDim.y - 1) / gridDim.y;
    const int start = chunk * per;
    const int end = min(start + per, SEG_L);
    for (int i = start + (int)threadIdx.x; i < end; i += (int)blockDim.x) {
        const float av = att[(long long)b * SEG_L + i];
        const unsigned key = ordkey(av);
        if (key > tk) {
            const float4* row = (const float4*)(x + ((size_t)b * SEG_L + i) * SEG_D);
            #pragma unroll
            for (int q = 0; q < 8; ++q) {
                float4 v = row[q];
                atomicAdd(&acc[q * 4 + 0], v.x);
                atomicAdd(&acc[q * 4 + 1], v.y);
                atomicAdd(&acc[q * 4 + 2], v.z);
                atomicAdd(&acc[q * 4 + 3], v.w);
            }
        } else if (key == tk) {
            unsigned pos = atomicAdd(&eq_cnt[b], 1u);
            if (pos < EQ_CAP) eq_idx[b * EQ_CAP + pos] = i;
        }
    }
    __syncthreads();
    if (threadIdx.x < SEG_D) atomicAdd(&g_acc[b * SEG_D + threadIdx.x], acc[threadIdx.x]);
}

// Pass 4: tie-break (take m smallest-index equals), mean over L, L2 normalize, write out.
__global__ void k_final(const float* __restrict__ x, const float* __restrict__ g_acc,
                        const unsigned* __restrict__ need_eq, const unsigned* __restrict__ eq_cnt,
                        const int* __restrict__ eq_idx, float* __restrict__ out) {
    const int b = blockIdx.x;
    __shared__ int chosen[TOPK];
    __shared__ float s_res[SEG_D];
    __shared__ float s_norm;
    const int m = (int)need_eq[b];
    const int cnt = min((int)eq_cnt[b], EQ_CAP);
    if (threadIdx.x == 0) {
        int last = -1;
        for (int j = 0; j < m; ++j) {
            int best = INT_MAX;
            for (int t = 0; t < cnt; ++t) {
                int v = eq_idx[b * EQ_CAP + t];
                if (v > last && v < best) best = v;
            }
            chosen[j] = best;
            last = (best == INT_MAX) ? last : best;
        }
    }
    __syncthreads();
    const int d = (int)threadIdx.x;
    if (d < SEG_D) {
        float s = g_acc[b * SEG_D + d];
        for (int j = 0; j < m; ++j) {
            int row = chosen[j];
            if (row != INT_MAX) s += x[((size_t)b * SEG_L + row) * SEG_D + d];
        }
        s_res[d] = s / (float)SEG_L;
    }
    __syncthreads();
    if (threadIdx.x == 0) {
        float n = 0.0f;
        for (int i = 0; i < SEG_D; ++i) n += s_res[i] * s_res[i];
        s_norm = sqrtf(n);
    }
    __syncthreads();
    if (d < SEG_D) {
        out[b * SEG_D + d] = s_res[d] / fmaxf(s_norm, 1e-12f);
    }
}

extern "C" void kernel_launch(void* const* d_in, const int* in_sizes, int n_in,
                              void* d_out, int out_size, void* d_ws, size_t ws_size,
                              hipStream_t stream) {
    const float* x    = (const float*)d_in[0];   // [B*L, 32] fp32
    // d_in[1] = length (int32[64]) — constant L, unused
    const float* w    = (const float*)d_in[2];   // [32]
    const float* bias = (const float*)d_in[3];   // [1]
    float* out = (float*)d_out;                  // [64, 32]

    // Workspace layout (all 4-byte aligned):
    char* p = (char*)d_ws;
    float*    att     = (float*)p;                 p += (size_t)SEG_B * SEG_L * sizeof(float);      // 12.8 MB
    float*    g_acc   = (float*)p;                 p += (size_t)SEG_B * SEG_D * sizeof(float);      // 8 KB
    unsigned* eq_cnt  = (unsigned*)p;              p += (size_t)SEG_B * sizeof(unsigned);           // 256 B
    unsigned* g_hist  = (unsigned*)p;              p += (size_t)SEG_B * 2048 * sizeof(unsigned);    // 512 KB
    unsigned* tkey    = (unsigned*)p;              p += (size_t)SEG_B * sizeof(unsigned);
    unsigned* need_eq = (unsigned*)p;              p += (size_t)SEG_B * sizeof(unsigned);
    int*      eq_idx  = (int*)p;                   p += (size_t)SEG_B * EQ_CAP * sizeof(int);       // 512 KB

    // Zero the atomically-accumulated regions (g_acc, eq_cnt, g_hist are contiguous).
    hipMemsetAsync(g_acc, 0,
                   (size_t)SEG_B * SEG_D * sizeof(float) + (size_t)SEG_B * sizeof(unsigned)
                   + (size_t)SEG_B * 2048 * sizeof(unsigned), stream);

    // Pass 1: attention scores + fused round-1 histogram (reads 409.6 MB of x — the HBM floor).
    dim3 gAH(CHUNKS, SEG_B);
    k_att_hist<<<gAH, 256, 0, stream>>>(x, w, bias, att, g_hist);

    // Pass 2: per-segment radix select of the 1024th-largest value (rounds 2+3 only).
    k_select<<<SEG_B, 1024, 0, stream>>>(att, g_hist, tkey, need_eq);

    // Pass 3: masked sum (strict >) + equal-index collection.
    dim3 g3(SEG_B, 16);
    k_accum<<<g3, 256, 0, stream>>>(x, att, tkey, g_acc, eq_cnt, eq_idx);

    // Pass 4: tie-break, mean, L2 normalize.
    k_final<<<SEG_B, 64, 0, stream>>>(x, g_acc, need_eq, eq_cnt, eq_idx, out);
}

// Round 3
// 723.810 us; speedup vs baseline: 1.0798x; 1.0798x over previous
//
#include <hip/hip_runtime.h>
#include <climits>

#define SEG_B 64
#define SEG_L 50000
#define SEG_D 32
#define TOPK  1024
#define EQ_CAP 2048

// Map float to uint32 such that larger float -> larger key (total order, no NaN in inputs).
__device__ __forceinline__ unsigned ordkey(float f) {
    unsigned u = __float_as_uint(f);
    return (u & 0x80000000u) ? ~u : (u | 0x80000000u);
}

// Pass 1: akey[p] = ordkey(dot(x[p,:32], w) + bias).  8 lanes per point, float4 loads
// (1 KiB/wave/instr). Stores the order-key directly: the float value is never needed again.
__global__ void k_att(const float* __restrict__ x, const float* __restrict__ w,
                      const float* __restrict__ bias, unsigned* __restrict__ akey) {
    const int lane = threadIdx.x & 63;
    const int q    = lane & 7;      // which float4 of the 32-dim row
    const int sub  = lane >> 3;     // which of the 8 points this wave handles per iter
    const int waveInBlock  = threadIdx.x >> 6;
    const int wavesPerBlock = blockDim.x >> 6;
    const long long waveId     = (long long)blockIdx.x * wavesPerBlock + waveInBlock;
    const long long totalWaves = (long long)gridDim.x * wavesPerBlock;
    const float4 wq = ((const float4*)w)[q];
    const float bb  = bias[0];
    const float4* x4 = (const float4*)x;
    const long long N = (long long)SEG_B * SEG_L;
    for (long long p = waveId * 8 + sub; p < N; p += totalWaves * 8) {
        float4 v = x4[p * 8 + q];
        float dot = v.x * wq.x + v.y * wq.y + v.z * wq.z + v.w * wq.w;
        dot += __shfl_xor(dot, 1);
        dot += __shfl_xor(dot, 2);
        dot += __shfl_xor(dot, 4);
        if (q == 0) akey[p] = ordkey(dot + bb);
    }
}

// Pass 2 (fused): per-segment 3-round radix select + index compaction + gather-sum +
// tie-break + mean + L2-normalize + output. One block per segment, 1024 threads.
// All scratch lives in LDS -> no global atomics, no memset, no extra kernels.
__global__ __launch_bounds__(1024) void k_fused(const float* __restrict__ x,
                                                const unsigned* __restrict__ akey,
                                                float* __restrict__ out) {
    const int b   = blockIdx.x;
    const int tid = (int)threadIdx.x;

    __shared__ unsigned hist[2048];
    __shared__ unsigned s_prefix, s_k;
    __shared__ int      s_sel[TOPK];
    __shared__ int      s_eq[EQ_CAP];
    __shared__ unsigned s_nsel, s_eqcnt, s_total;
    __shared__ float    s_acc[SEG_D];
    __shared__ float    s_res[SEG_D];
    __shared__ float    s_norm;

    const unsigned* a = akey + (long long)b * SEG_L;

    if (tid == 0) { s_prefix = 0u; s_k = TOPK; s_nsel = 0u; s_eqcnt = 0u; }

    // ---- 3-round radix select (11/11/10 bits, descending) ----
    const unsigned shifts[3]   = {21u, 10u, 0u};
    const unsigned widths[3]   = {11u, 11u, 10u};
    const unsigned maskdone[3] = {0x00000000u, 0xFFE00000u, 0xFFFFFC00u};

    for (int r = 0; r < 3; ++r) {
        const unsigned shift = shifts[r];
        const unsigned nbins = 1u << widths[r];
        const unsigned dmask = nbins - 1u;
        const unsigned mdone = maskdone[r];
        for (int i = tid; i < 2048; i += 1024) hist[i] = 0u;
        __syncthreads();                      // hist zeroed + previous round's s_prefix visible
        const unsigned prefix = s_prefix;
        for (int i = tid; i < SEG_L; i += 1024) {
            unsigned key = a[i];
            if ((key & mdone) == prefix) {
                atomicAdd(&hist[(key >> shift) & dmask], 1u);
            }
        }
        __syncthreads();
        if (tid == 0) {
            unsigned k = s_k, acc = 0u; unsigned digit = 0u;
            for (int bin = (int)nbins - 1; bin >= 0; --bin) {
                unsigned c = hist[bin];
                if (acc + c >= k) { digit = (unsigned)bin; s_k = k - acc; break; }
                acc += c;
            }
            s_prefix = prefix | (digit << shift);
        }
        __syncthreads();                      // protect hist + publish s_prefix/s_k
    }
    const unsigned tk = s_prefix;
    const int m = (int)s_k;                   // equals needed (>=1 always)

    // ---- compact selected (strictly greater) + equal indices into LDS ----
    for (int i = tid; i < SEG_L; i += 1024) {
        unsigned key = a[i];
        if (key > tk) {
            unsigned pos = atomicAdd(&s_nsel, 1u);
            if (pos < TOPK) s_sel[pos] = i;   // #greater <= TOPK-1 by construction
        } else if (key == tk) {
            unsigned pos = atomicAdd(&s_eqcnt, 1u);
            if (pos < EQ_CAP) s_eq[pos] = i;
        }
    }
    __syncthreads();

    // ---- tie-break: append m smallest equal indices ----
    if (tid == 0) {
        int nsel = min((int)s_nsel, TOPK);
        int cnt  = min((int)s_eqcnt, EQ_CAP);
        int last = -1, appended = 0;
        for (int j = 0; j < m && nsel + appended < TOPK; ++j) {
            int best = INT_MAX;
            for (int t = 0; t < cnt; ++t) {
                int v = s_eq[t];
                if (v > last && v < best) best = v;
            }
            if (best == INT_MAX) break;
            s_sel[nsel + appended] = best;
            ++appended; last = best;
        }
        s_total = (unsigned)(nsel + appended);
    }
    if (tid < SEG_D) s_acc[tid] = 0.0f;
    __syncthreads();

    // ---- gather-sum the selected rows: register float4 acc + shfl reduce ----
    const int lane = tid & 63;
    const int q    = lane & 7;                // which float4 of the row
    const int sub  = lane >> 3;               // which of 8 rows per wave-iter
    const int wv   = tid >> 6;                // wave index 0..15
    const float4* x4 = (const float4*)x;
    const long long segBase = (long long)b * SEG_L;
    const int total = (int)s_total;
    float4 f = make_float4(0.f, 0.f, 0.f, 0.f);
    for (int j = wv * 8 + sub; j < total; j += 128) {
        const long long p = segBase + s_sel[j];
        float4 v = x4[p * 8 + q];
        f.x += v.x; f.y += v.y; f.z += v.z; f.w += v.w;
    }
    #pragma unroll
    for (int off = 8; off <= 32; off <<= 1) { // reduce across the 8 'sub' row-slots
        f.x += __shfl_xor(f.x, off);
        f.y += __shfl_xor(f.y, off);
        f.z += __shfl_xor(f.z, off);
        f.w += __shfl_xor(f.w, off);
    }
    if (sub == 0) {                           // 8 lanes/wave, 16 waves -> 512 light atomics
        atomicAdd(&s_acc[q * 4 + 0], f.x);
        atomicAdd(&s_acc[q * 4 + 1], f.y);
        atomicAdd(&s_acc[q * 4 + 2], f.z);
        atomicAdd(&s_acc[q * 4 + 3], f.w);
    }
    __syncthreads();

    // ---- mean over L, L2 normalize, write ----
    if (tid == 0) {
        float n = 0.0f;
        for (int i = 0; i < SEG_D; ++i) {
            float v = s_acc[i] / (float)SEG_L;
            s_res[i] = v;
            n += v * v;
        }
        s_norm = sqrtf(n);
    }
    __syncthreads();
    if (tid < SEG_D) {
        out[b * SEG_D + tid] = s_res[tid] / fmaxf(s_norm, 1e-12f);
    }
}

extern "C" void kernel_launch(void* const* d_in, const int* in_sizes, int n_in,
                              void* d_out, int out_size, void* d_ws, size_t ws_size,
                              hipStream_t stream) {
    const float* x    = (const float*)d_in[0];   // [B*L, 32] fp32
    // d_in[1] = length (int32[64]) — constant L, unused
    const float* w    = (const float*)d_in[2];   // [32]
    const float* bias = (const float*)d_in[3];   // [1]
    float* out = (float*)d_out;                  // [64, 32]

    // Workspace: only the order-keys. No memset needed (all scratch is in LDS).
    unsigned* akey = (unsigned*)d_ws;            // [B*L] = 12.8 MB

    // Pass 1: attention order-keys (reads 409.6 MB of x — the HBM floor).
    k_att<<<2048, 256, 0, stream>>>(x, w, bias, akey);

    // Pass 2: fused select + gather + normalize. One block per segment.
    k_fused<<<SEG_B, 1024, 0, stream>>>(x, akey, out);
}

// Round 4
// 553.338 us; speedup vs baseline: 1.4124x; 1.3081x over previous
//
#include <hip/hip_runtime.h>
#include <climits>

#define SEG_B 64
#define SEG_L 50000
#define SEG_D 32
#define TOPK  1024
#define EQ_CAP 2048
#define CAND_CAP 8192
#define NVEC (SEG_L / 4)   // 12500 uint4 per segment (50000 % 4 == 0)

// Map float to uint32 such that larger float -> larger key (total order, no NaN in inputs).
__device__ __forceinline__ unsigned ordkey(float f) {
    unsigned u = __float_as_uint(f);
    return (u & 0x80000000u) ? ~u : (u | 0x80000000u);
}

// Pass 1: akey[p] = ordkey(dot(x[p,:32], w) + bias).  8 lanes per point, float4 loads
// (1 KiB/wave/instr). Stores the order-key directly: the float value is never needed again.
__global__ void k_att(const float* __restrict__ x, const float* __restrict__ w,
                      const float* __restrict__ bias, unsigned* __restrict__ akey) {
    const int lane = threadIdx.x & 63;
    const int q    = lane & 7;      // which float4 of the 32-dim row
    const int sub  = lane >> 3;     // which of the 8 points this wave handles per iter
    const int waveInBlock  = threadIdx.x >> 6;
    const int wavesPerBlock = blockDim.x >> 6;
    const long long waveId     = (long long)blockIdx.x * wavesPerBlock + waveInBlock;
    const long long totalWaves = (long long)gridDim.x * wavesPerBlock;
    const float4 wq = ((const float4*)w)[q];
    const float bb  = bias[0];
    const float4* x4 = (const float4*)x;
    const long long N = (long long)SEG_B * SEG_L;
    for (long long p = waveId * 8 + sub; p < N; p += totalWaves * 8) {
        float4 v = x4[p * 8 + q];
        float dot = v.x * wq.x + v.y * wq.y + v.z * wq.z + v.w * wq.w;
        dot += __shfl_xor(dot, 1);
        dot += __shfl_xor(dot, 2);
        dot += __shfl_xor(dot, 4);
        if (q == 0) akey[p] = ordkey(dot + bb);
    }
}

// Block-parallel descending threshold find: given hist[nbins] (nbins 2048 or 1024) and k,
// find the largest digit such that suffix-sum(digit) >= k; rem = k - suffix-sum(digit+1).
// 1024 threads; thread order = descending bins; two-level inclusive scan (shfl_up + wave
// totals). Replaces the serial thread-0 walk (~500-1000 dependent LDS reads @ ~120cyc).
__device__ __forceinline__ void find_digit(const unsigned* hist, int nbins, unsigned k,
                                           unsigned* wsum, unsigned* s_digit, unsigned* s_rem) {
    const int tid  = (int)threadIdx.x;
    const int lane = tid & 63;
    const int wv   = tid >> 6;
    unsigned a0, a1 = 0u, s;
    if (nbins == 2048) {
        a0 = hist[2047 - 2 * tid];
        a1 = hist[2047 - (2 * tid + 1)];
        s  = a0 + a1;
    } else {
        a0 = hist[1023 - tid];
        s  = a0;
    }
    unsigned v = s;
    #pragma unroll
    for (int off = 1; off < 64; off <<= 1) {
        unsigned u = __shfl_up(v, off);
        if (lane >= off) v += u;
    }
    if (lane == 63) wsum[wv] = v;
    __syncthreads();
    if (tid < 16) {
        unsigned t = wsum[tid];
        #pragma unroll
        for (int off = 1; off < 16; off <<= 1) {
            unsigned u = __shfl_up(t, off);
            if (tid >= off) t += u;
        }
        wsum[tid] = t;   // inclusive wave-total scan
    }
    __syncthreads();
    const unsigned waveOff = (wv == 0) ? 0u : wsum[wv - 1];
    const unsigned incl = v + waveOff;       // suffix count through this thread's bins
    const unsigned excl = incl - s;          // suffix count above this thread's bins
    if (excl < k && k <= incl) {             // exactly one thread crosses
        if (nbins == 2048) {
            if (excl + a0 >= k) { *s_digit = (unsigned)(2047 - 2 * tid); *s_rem = k - excl; }
            else { *s_digit = (unsigned)(2047 - (2 * tid + 1)); *s_rem = k - (excl + a0); }
        } else {
            *s_digit = (unsigned)(1023 - tid); *s_rem = k - excl;
        }
    }
    __syncthreads();
}

// Pass 2 (fused): per-segment radix select + gather + normalize. One block per segment,
// 1024 threads. Fast path: after round 1, compact the threshold bin's candidates into LDS
// (Gaussian att -> threshold bin ~1-3k values) so rounds 2/3 + extraction run in-LDS:
// only TWO global sweeps of akey. Block-uniform fallback to global sweeps on overflow.
__global__ __launch_bounds__(1024) void k_fused(const float* __restrict__ x,
                                                const unsigned* __restrict__ akey,
                                                float* __restrict__ out) {
    const int b   = blockIdx.x;
    const int tid = (int)threadIdx.x;

    __shared__ unsigned hist[2048];
    __shared__ unsigned wsum[16];
    __shared__ unsigned s_digit, s_rem;
    __shared__ unsigned s_nsel, s_ncand, s_eqcnt, s_total;
    __shared__ int      s_sel[TOPK];
    __shared__ int      s_eq[EQ_CAP];
    __shared__ int      cand_i[CAND_CAP];
    __shared__ unsigned cand_k[CAND_CAP];
    __shared__ float    s_acc[SEG_D];
    __shared__ float    s_res[SEG_D];
    __shared__ float    s_norm;

    const unsigned* a  = akey + (long long)b * SEG_L;
    const uint4*    a4 = (const uint4*)a;

    if (tid == 0) { s_nsel = 0u; s_ncand = 0u; s_eqcnt = 0u; }
    for (int i = tid; i < 2048; i += 1024) hist[i] = 0u;
    __syncthreads();

    // ---- global sweep 1: histogram of top 11 bits (uint4 loads) ----
    for (int i = tid; i < NVEC; i += 1024) {
        uint4 kk = a4[i];
        atomicAdd(&hist[kk.x >> 21], 1u);
        atomicAdd(&hist[kk.y >> 21], 1u);
        atomicAdd(&hist[kk.z >> 21], 1u);
        atomicAdd(&hist[kk.w >> 21], 1u);
    }
    __syncthreads();
    find_digit(hist, 2048, TOPK, wsum, &s_digit, &s_rem);
    const unsigned d1 = s_digit;
    const unsigned k2 = s_rem;                 // remaining k within bin d1 (>=1)

    for (int i = tid; i < 2048; i += 1024) hist[i] = 0u;
    __syncthreads();

    // ---- global sweep 2: strict-top compaction + candidate compaction + round-2 hist ----
    for (int i = tid; i < NVEC; i += 1024) {
        uint4 kk = a4[i];
        unsigned kv[4] = {kk.x, kk.y, kk.z, kk.w};
        const int base = i * 4;
        #pragma unroll
        for (int c = 0; c < 4; ++c) {
            const unsigned key = kv[c];
            const unsigned hi = key >> 21;
            if (hi > d1) {
                unsigned pos = atomicAdd(&s_nsel, 1u);
                if (pos < TOPK) s_sel[pos] = base + c;       // count = TOPK-k2 <= 1023
            } else if (hi == d1) {
                unsigned pos = atomicAdd(&s_ncand, 1u);
                if (pos < CAND_CAP) {
                    cand_i[pos] = base + c;
                    cand_k[pos] = key;
                    atomicAdd(&hist[(key >> 10) & 0x7FFu], 1u);
                }
            }
        }
    }
    __syncthreads();

    const int ncand = (int)s_ncand;
    unsigned tk;
    int m;

    if (ncand <= CAND_CAP) {
        // ---- fast path: rounds 2/3 + extraction entirely on in-LDS candidates ----
        find_digit(hist, 2048, k2, wsum, &s_digit, &s_rem);
        const unsigned d2 = s_digit;
        const unsigned k3 = s_rem;
        hist[tid] = 0u;                        // zero round-3 bins (1024)
        __syncthreads();
        const unsigned pref23 = (d1 << 11) | d2;   // pattern of key>>10
        for (int j = tid; j < ncand; j += 1024) {
            const unsigned key = cand_k[j];
            if ((key >> 10) == pref23) atomicAdd(&hist[key & 0x3FFu], 1u);
        }
        __syncthreads();
        find_digit(hist, 1024, k3, wsum, &s_digit, &s_rem);
        tk = (d1 << 21) | (d2 << 10) | s_digit;
        m  = (int)s_rem;
        for (int j = tid; j < ncand; j += 1024) {
            const unsigned key = cand_k[j];
            if (key > tk) {
                unsigned pos = atomicAdd(&s_nsel, 1u);
                if (pos < TOPK) s_sel[pos] = cand_i[j];
            } else if (key == tk) {
                unsigned pos = atomicAdd(&s_eqcnt, 1u);
                if (pos < EQ_CAP) s_eq[pos] = cand_i[j];
            }
        }
        __syncthreads();
    } else {
        // ---- fallback: candidate bin overflowed LDS; do global-sweep rounds 2/3 ----
        for (int i = tid; i < 2048; i += 1024) hist[i] = 0u;
        __syncthreads();
        for (int i = tid; i < SEG_L; i += 1024) {
            const unsigned key = a[i];
            if ((key >> 21) == d1) atomicAdd(&hist[(key >> 10) & 0x7FFu], 1u);
        }
        __syncthreads();
        find_digit(hist, 2048, k2, wsum, &s_digit, &s_rem);
        const unsigned d2 = s_digit;
        const unsigned k3 = s_rem;
        hist[tid] = 0u;
        __syncthreads();
        const unsigned pref23 = (d1 << 11) | d2;
        for (int i = tid; i < SEG_L; i += 1024) {
            const unsigned key = a[i];
            if ((key >> 10) == pref23) atomicAdd(&hist[key & 0x3FFu], 1u);
        }
        __syncthreads();
        find_digit(hist, 1024, k3, wsum, &s_digit, &s_rem);
        tk = (d1 << 21) | (d2 << 10) | s_digit;
        m  = (int)s_rem;
        for (int i = tid; i < SEG_L; i += 1024) {
            const unsigned key = a[i];
            if ((key >> 21) == d1) {           // strict-top (hi>d1) already in s_sel
                if (key > tk) {
                    unsigned pos = atomicAdd(&s_nsel, 1u);
                    if (pos < TOPK) s_sel[pos] = i;
                } else if (key == tk) {
                    unsigned pos = atomicAdd(&s_eqcnt, 1u);
                    if (pos < EQ_CAP) s_eq[pos] = i;
                }
            }
        }
        __syncthreads();
    }

    // ---- tie-break: append m smallest equal indices (m is typically 1 for random floats) ----
    if (tid == 0) {
        int nsel = min((int)s_nsel, TOPK);
        int cnt  = min((int)s_eqcnt, EQ_CAP);
        int last = -1, appended = 0;
        for (int j = 0; j < m && nsel + appended < TOPK; ++j) {
            int best = INT_MAX;
            for (int t = 0; t < cnt; ++t) {
                int v = s_eq[t];
                if (v > last && v < best) best = v;
            }
            if (best == INT_MAX) break;
            s_sel[nsel + appended] = best;
            ++appended; last = best;
        }
        s_total = (unsigned)(nsel + appended);
    }
    if (tid < SEG_D) s_acc[tid] = 0.0f;
    __syncthreads();

    // ---- gather-sum the selected rows: register float4 acc + shfl reduce ----
    const int lane = tid & 63;
    const int q    = lane & 7;                // which float4 of the row
    const int sub  = lane >> 3;               // which of 8 rows per wave-iter
    const int wv   = tid >> 6;                // wave index 0..15
    const float4* x4 = (const float4*)x;
    const long long segBase = (long long)b * SEG_L;
    const int total = (int)s_total;
    float4 f = make_float4(0.f, 0.f, 0.f, 0.f);
    for (int j = wv * 8 + sub; j < total; j += 128) {
        const long long p = segBase + s_sel[j];
        float4 v = x4[p * 8 + q];
        f.x += v.x; f.y += v.y; f.z += v.z; f.w += v.w;
    }
    #pragma unroll
    for (int off = 8; off <= 32; off <<= 1) { // reduce across the 8 'sub' row-slots
        f.x += __shfl_xor(f.x, off);
        f.y += __shfl_xor(f.y, off);
        f.z += __shfl_xor(f.z, off);
        f.w += __shfl_xor(f.w, off);
    }
    if (sub == 0) {                           // 8 lanes/wave, 16 waves -> 512 light atomics
        atomicAdd(&s_acc[q * 4 + 0], f.x);
        atomicAdd(&s_acc[q * 4 + 1], f.y);
        atomicAdd(&s_acc[q * 4 + 2], f.z);
        atomicAdd(&s_acc[q * 4 + 3], f.w);
    }
    __syncthreads();

    // ---- mean over L, L2 normalize, write ----
    if (tid == 0) {
        float n = 0.0f;
        for (int i = 0; i < SEG_D; ++i) {
            float v = s_acc[i] / (float)SEG_L;
            s_res[i] = v;
            n += v * v;
        }
        s_norm = sqrtf(n);
    }
    __syncthreads();
    if (tid < SEG_D) {
        out[b * SEG_D + tid] = s_res[tid] / fmaxf(s_norm, 1e-12f);
    }
}

extern "C" void kernel_launch(void* const* d_in, const int* in_sizes, int n_in,
                              void* d_out, int out_size, void* d_ws, size_t ws_size,
                              hipStream_t stream) {
    const float* x    = (const float*)d_in[0];   // [B*L, 32] fp32
    // d_in[1] = length (int32[64]) — constant L, unused
    const float* w    = (const float*)d_in[2];   // [32]
    const float* bias = (const float*)d_in[3];   // [1]
    float* out = (float*)d_out;                  // [64, 32]

    // Workspace: only the order-keys. No memset needed (all scratch is in LDS).
    unsigned* akey = (unsigned*)d_ws;            // [B*L] = 12.8 MB

    // Pass 1: attention order-keys (reads 409.6 MB of x — the HBM floor).
    k_att<<<2048, 256, 0, stream>>>(x, w, bias, akey);

    // Pass 2: fused select + gather + normalize. One block per segment.
    k_fused<<<SEG_B, 1024, 0, stream>>>(x, akey, out);
}